// Round 14
// baseline (40.935 us; speedup 1.0000x reference)
//
#include <hip/hip_runtime.h>
#include <hip/hip_bf16.h>

#define BB 16
#define NN 512
#define DIN 256
#define DOUT 256
#define HH 8
#define HD 32
#define EE 131072
#define MM (BB*NN)    // 8192 rows
#define BH (BB*HH)    // 128

typedef unsigned short ushort_t;
typedef __attribute__((ext_vector_type(8))) short bf16x8;
typedef __attribute__((ext_vector_type(4))) float f32x4;

__device__ __forceinline__ unsigned short f2bf(float f) {
    unsigned int u = __float_as_uint(f);
    unsigned int r = (u + 0x7fffu + ((u >> 16) & 1u)) >> 16;
    return (unsigned short)r;
}

// async global->LDS, 16B per lane; dest = wave-uniform base + lane*16 (HW rule)
__device__ __forceinline__ void gload16(const ushort_t* g, ushort_t* l) {
    __builtin_amdgcn_global_load_lds((__attribute__((address_space(1))) void*)(void*)g,
                                     (__attribute__((address_space(3))) void*)l, 16, 0, 0);
}

// unpack 16 bf16 (32B) -> 16 fp32
__device__ __forceinline__ void ld16bf(const ushort_t* p, float* f) {
    uint4 u0 = *(const uint4*)p;
    uint4 u1 = *(const uint4*)(p + 8);
    unsigned int w[8] = {u0.x, u0.y, u0.z, u0.w, u1.x, u1.y, u1.z, u1.w};
    #pragma unroll
    for (int i = 0; i < 8; ++i) {
        f[2 * i]     = __uint_as_float(w[i] << 16);
        f[2 * i + 1] = __uint_as_float(w[i] & 0xffff0000u);
    }
}

// ---------------- K1 prep: zero mask | h fp32->bf16 (XCD-aligned) | LDS-tiled W transpose ----------------
__global__ __launch_bounds__(256) void prep(
    const float* __restrict__ h,
    const float* __restrict__ Wq, const float* __restrict__ Wk,
    const float* __restrict__ Wv, const float* __restrict__ Wo,
    unsigned int* __restrict__ mask, ushort_t* __restrict__ hb,
    ushort_t* __restrict__ Wt, ushort_t* __restrict__ Wot) {
    __shared__ float ts[64][65];
    const int bid = blockIdx.x;
    const int t = threadIdx.x;
    if (bid < 128) {
        uint4 z = {0u, 0u, 0u, 0u};
        ((uint4*)mask)[bid * 256 + t] = z;        // 512 KB
    } else if (bid < 1152) {
        // h2bf, XCD-aligned with the QKV GEMM reader
        int j = bid - 128;                        // 0..1023
        int jj = (j & 7) * 128 + (j >> 3);
        int chunk = jj * 256 + t;                 // 262144 chunks of 8 floats
        float4 a = *(const float4*)(h + (size_t)chunk * 8);
        float4 b = *(const float4*)(h + (size_t)chunk * 8 + 4);
        ushort_t o[8] = {f2bf(a.x), f2bf(a.y), f2bf(a.z), f2bf(a.w),
                         f2bf(b.x), f2bf(b.y), f2bf(b.z), f2bf(b.w)};
        *(uint4*)(hb + (size_t)chunk * 8) = *(const uint4*)o;
    } else {
        // coalesced transpose: which W, 16 tiles of 64x64 each
        const int bid6 = bid - 1152;
        const int which = bid6 >> 4, tile = bid6 & 15;
        const int k0 = (tile >> 2) * 64, n0 = (tile & 3) * 64;
        const float* W = (which == 0) ? Wq : (which == 1) ? Wk : (which == 2) ? Wv : Wo;
        #pragma unroll
        for (int i = 0; i < 4; ++i) {
            int kr = i * 16 + (t >> 4), c4 = (t & 15) * 4;
            float4 v = *(const float4*)&W[(size_t)(k0 + kr) * 256 + n0 + c4];
            ts[kr][c4 + 0] = v.x; ts[kr][c4 + 1] = v.y;
            ts[kr][c4 + 2] = v.z; ts[kr][c4 + 3] = v.w;
        }
        __syncthreads();
        #pragma unroll
        for (int i = 0; i < 4; ++i) {
            int nr = i * 16 + (t >> 4), kc = (t & 15) * 4;
            ushort_t o[4] = {f2bf(ts[kc][nr]), f2bf(ts[kc + 1][nr]),
                             f2bf(ts[kc + 2][nr]), f2bf(ts[kc + 3][nr])};
            ushort_t* dstp = (which < 3) ? (Wt + (size_t)(which * 256 + n0 + nr) * 256 + k0 + kc)
                                         : (Wot + (size_t)(n0 + nr) * 256 + k0 + kc);
            *(uint2*)dstp = *(const uint2*)o;
        }
    }
}

// ---------------- K2: QKV GEMM (blocks 0-383, XCD-swizzled, BK=128) || mask_build (384-895) ----------------
// q/k/v outputs ROW-MAJOR [8192][256] (head-interleaved) for coalesced attn gathers.
__global__ __launch_bounds__(256) void mask_gemm(
    const int* __restrict__ src, const int* __restrict__ dst, unsigned int* __restrict__ mask,
    const ushort_t* __restrict__ A, const ushort_t* __restrict__ Bt,
    const float* __restrict__ b0, const float* __restrict__ b1, const float* __restrict__ b2,
    ushort_t* __restrict__ qb, ushort_t* __restrict__ kb, ushort_t* __restrict__ vb) {
    __shared__ ushort_t As[128 * 128];   // 32 KB
    __shared__ ushort_t Bs[128 * 128];   // 32 KB
    const int bid = blockIdx.x;
    const int t = threadIdx.x;

    if (bid >= 384) {
        // ---- mask build ----
        int tt = (bid - 384) * 256 + t;
        if (tt < EE) {
            int s = src[tt], d = dst[tt];
            int b = s / NN, r = s % NN, c = d % NN;
            atomicOr(&mask[((size_t)(b * NN + r)) * 16 + (c >> 5)], 1u << (c & 31));
        }
        if (tt < MM) {
            atomicOr(&mask[(size_t)tt * 16 + ((tt & 511) >> 5)], 1u << (tt & 31));
        }
        return;
    }

    // ---- QKV GEMM; T1 swizzle: XCD x gets contiguous 8m x 6n region (384 = 8*48, bijective) ----
    const int xcd = bid & 7, idx = bid >> 3;       // idx in [0,48)
    const int m0 = (xcd * 8 + (idx & 7)) * 128;    // 64 m-tiles
    const int n0 = (idx >> 3) * 128;               // 6 n-tiles
    const int wid = t >> 6, lane = t & 63, g = lane >> 4, c = lane & 15;
    const int wr = wid >> 1, wc = wid & 1;

    f32x4 acc[4][4];
    #pragma unroll
    for (int mi = 0; mi < 4; ++mi)
        #pragma unroll
        for (int nj = 0; nj < 4; ++nj) acc[mi][nj] = (f32x4){0.f, 0.f, 0.f, 0.f};

    // BK=128: 16 x 16B slots per row; swizzle slot ^= (row & 15), both sides (rule 21)
    #define STAGE_QKV(kt) { \
        const int k0s = (kt) * 128; \
        _Pragma("unroll") \
        for (int i = 0; i < 8; ++i) { \
            int p = i * 256 + t; \
            int row = p >> 4, ss = (p & 15) ^ (row & 15); \
            int ldoff = (i * 256 + wid * 64) * 8; \
            gload16(A  + (size_t)(m0 + row) * 256 + k0s + ss * 8, &As[ldoff]); \
            gload16(Bt + (size_t)(n0 + row) * 256 + k0s + ss * 8, &Bs[ldoff]); \
        } \
    }

    STAGE_QKV(0);
    __syncthreads();
    for (int kt = 0; kt < 2; ++kt) {
        #pragma unroll
        for (int kk = 0; kk < 4; ++kk) {
            bf16x8 av[4], bv4[4];
            #pragma unroll
            for (int mi = 0; mi < 4; ++mi) {
                int row = wr * 64 + mi * 16 + c;                 // row & 15 == c
                av[mi] = *(const bf16x8*)&As[row * 128 + (((kk * 4 + g) ^ c) << 3)];
            }
            #pragma unroll
            for (int nj = 0; nj < 4; ++nj) {
                int row = wc * 64 + nj * 16 + c;
                bv4[nj] = *(const bf16x8*)&Bs[row * 128 + (((kk * 4 + g) ^ c) << 3)];
            }
            #pragma unroll
            for (int mi = 0; mi < 4; ++mi)
                #pragma unroll
                for (int nj = 0; nj < 4; ++nj)
                    acc[mi][nj] = __builtin_amdgcn_mfma_f32_16x16x32_bf16(av[mi], bv4[nj], acc[mi][nj], 0, 0, 0);
        }
        if (kt == 0) {
            __syncthreads();
            STAGE_QKV(1);
            __syncthreads();
        }
    }

    #pragma unroll
    for (int mi = 0; mi < 4; ++mi) {
        #pragma unroll
        for (int nj = 0; nj < 4; ++nj) {
            const f32x4 av = acc[mi][nj];
            const int m_base = m0 + wr * 64 + mi * 16 + 4 * g;
            const int n_base = n0 + wc * 64 + nj * 16;
            const int z = n_base >> 8, nn = n_base & 255;
            const float* bp = (z == 0) ? b0 : (z == 1) ? b1 : b2;
            const float bias = bp[nn + c];
            ushort_t* dst2 = (z == 0) ? qb : (z == 1) ? kb : vb;
            #pragma unroll
            for (int r = 0; r < 4; ++r)
                dst2[(size_t)(m_base + r) * 256 + nn + c] = f2bf(av[r] + bias);
        }
    }
}

// ---------------- K3: fused sparse attention + out-proj ----------------
// 512 blocks x 1024 threads (16 waves). XCD swizzle: xcd = bid&7 -> graphs {2x,2x+1}.
// Phase A: wave w = one row (16 rows/block, FULL row-wave parallelism: 8192 waves)
//          validated gather body -> Atile[16][264] bf16.
// Phase B: wave w = one 16x16 output n-tile; A-frags from Atile, B-frags直接 from
//          L2-resident Wot (no staging); bias; fp32 store. Same MFMA conventions.
__global__ __launch_bounds__(1024) void attn_out(
    const ushort_t* __restrict__ qb, const ushort_t* __restrict__ kb,
    const ushort_t* __restrict__ vb, const unsigned int* __restrict__ mask,
    const ushort_t* __restrict__ Wot, const float* __restrict__ bo,
    float* __restrict__ fout) {
    __shared__ ushort_t Atile[16][264];
    __shared__ ushort_t colsS[16][64];
    const int t = threadIdx.x;
    const int wid = t >> 6, lane = t & 63;
    const int xcd = blockIdx.x & 7, j = blockIdx.x >> 3;   // 512 blocks, j in [0,64)
    const int b = 2 * xcd + (j >> 5);                      // graph
    const int q0 = (j & 31) * 16;
    const int q = q0 + wid;                                // this wave's row
    const int row = b * 512 + q;
    const int e2 = lane >> 4, h = (lane >> 1) & 7, half = lane & 1;
    const int g = lane >> 4, c = lane & 15;
    const float SCALE = 0.17677669529663687f;  // 1/sqrt(32)

    // ---------------- Phase A (validated body, one row per wave) ----------------
    {
        unsigned int word = (lane < 16) ? mask[(size_t)row * 16 + lane] : 0u;
        int pc = __popc(word);
        int pre = pc;
        #pragma unroll
        for (int o = 1; o < 16; o <<= 1) {
            int v = __shfl_up(pre, o);
            if ((lane & 15) >= o) pre += v;
        }
        int off = pre - pc;
        while (word) {
            int bit = __ffs(word) - 1;
            word &= word - 1;
            if (off < 64) colsS[wid][off] = (ushort_t)(lane * 32 + bit);
            ++off;
        }
        int cnt = __shfl(pre, 15);
        cnt = cnt < 64 ? cnt : 64;

        const size_t rowbase = (size_t)b * 512;
        const int hd0 = h * 32 + half * 16;
        float qf[16];
        ld16bf(qb + (rowbase + q) * 256 + hd0, qf);

        float acc[16];
        #pragma unroll
        for (int d = 0; d < 16; ++d) acc[d] = 0.f;
        float l = 0.f;

        #pragma unroll 2
        for (int e = 0; e < cnt; e += 4) {
            int slot = e + e2;
            int col = colsS[wid][slot < cnt ? slot : 0];
            const ushort_t* kp = kb + (rowbase + col) * 256 + hd0;
            const ushort_t* vp = vb + (rowbase + col) * 256 + hd0;
            float kf[16], vf[16];
            ld16bf(kp, kf);
            ld16bf(vp, vf);
            float s0 = 0.f, s1 = 0.f;
            #pragma unroll
            for (int d = 0; d < 8; ++d) {
                s0 = fmaf(qf[d], kf[d], s0);
                s1 = fmaf(qf[8 + d], kf[8 + d], s1);
            }
            float s = s0 + s1;
            s += __shfl_xor(s, 1);
            float p = (slot < cnt) ? __expf(fmaf(s, SCALE, -16.0f)) : 0.f;
            l += p;
            #pragma unroll
            for (int d = 0; d < 16; ++d) acc[d] = fmaf(p, vf[d], acc[d]);
        }

        #pragma unroll
        for (int d = 0; d < 16; ++d) {
            acc[d] += __shfl_xor(acc[d], 16);
            acc[d] += __shfl_xor(acc[d], 32);
        }
        l += __shfl_xor(l, 16);
        l += __shfl_xor(l, 32);

        if (e2 == 0) {
            float rl = 1.0f / l;
            ushort_t o[16];
            #pragma unroll
            for (int d = 0; d < 16; ++d) o[d] = f2bf(acc[d] * rl);
            ushort_t* op = &Atile[wid][hd0];
            *(uint4*)op       = *(const uint4*)o;
            *(uint4*)(op + 8) = *(const uint4*)(o + 8);
        }
    }
    __syncthreads();

    // ---------------- Phase B: [16][256] @ Wot^T, wave wid owns n-cols [wid*16, wid*16+16) ----------------
    f32x4 oacc = {0.f, 0.f, 0.f, 0.f};
    #pragma unroll
    for (int kk = 0; kk < 8; ++kk) {
        bf16x8 af = *(const bf16x8*)&Atile[c][kk * 32 + 8 * g];
        bf16x8 bf = *(const bf16x8*)(Wot + (size_t)(wid * 16 + c) * 256 + kk * 32 + 8 * g);
        oacc = __builtin_amdgcn_mfma_f32_16x16x32_bf16(af, bf, oacc, 0, 0, 0);
    }
    const int gr0 = b * 512 + q0;
    const int ncol = wid * 16 + c;
    const float bias = bo[ncol];
    #pragma unroll
    for (int r = 0; r < 4; ++r)
        fout[(size_t)(gr0 + 4 * g + r) * 256 + ncol] = oacc[r] + bias;
}

extern "C" void kernel_launch(void* const* d_in, const int* in_sizes, int n_in,
                              void* d_out, int out_size, void* d_ws, size_t ws_size,
                              hipStream_t stream) {
    const float* hin = (const float*)d_in[0];
    const int* src   = (const int*)d_in[1];
    const int* dst   = (const int*)d_in[2];
    const float* Wq  = (const float*)d_in[3];
    const float* bq  = (const float*)d_in[4];
    const float* Wk  = (const float*)d_in[5];
    const float* bk  = (const float*)d_in[6];
    const float* Wv  = (const float*)d_in[7];
    const float* bv  = (const float*)d_in[8];
    const float* Wo  = (const float*)d_in[9];
    const float* bo  = (const float*)d_in[10];

    char* ws = (char*)d_ws;
    unsigned int* mask = (unsigned int*)ws;                      // 512 KB
    ushort_t* hb    = (ushort_t*)(ws + 2129920);                 // 4 MB
    ushort_t* qb    = (ushort_t*)(ws + 6324224);                 // 4 MB
    ushort_t* kb    = (ushort_t*)(ws + 10518528);                // 4 MB
    ushort_t* vb    = (ushort_t*)(ws + 14712832);                // 4 MB
    ushort_t* Wt    = (ushort_t*)(ws + 23101440);                // 384 KB
    ushort_t* Wot   = (ushort_t*)(ws + 23494656);                // 128 KB
    float* out = (float*)d_out;

    prep<<<1216, 256, 0, stream>>>(hin, Wq, Wk, Wv, Wo, mask, hb, Wt, Wot);
    mask_gemm<<<896, 256, 0, stream>>>(src, dst, mask, hb, Wt, bq, bk, bv, qb, kb, vb);
    attn_out<<<512, 1024, 0, stream>>>(qb, kb, vb, mask, Wot, bo, out);
}

// Round 15
// 37.404 us; speedup vs baseline: 1.0944x; 1.0944x over previous
//
#include <hip/hip_runtime.h>
#include <hip/hip_bf16.h>

#define BB 16
#define NN 512
#define DIN 256
#define DOUT 256
#define HH 8
#define HD 32
#define EE 131072
#define MM (BB*NN)    // 8192 rows
#define BH (BB*HH)    // 128

typedef unsigned short ushort_t;
typedef __attribute__((ext_vector_type(8))) short bf16x8;
typedef __attribute__((ext_vector_type(4))) float f32x4;

__device__ __forceinline__ unsigned short f2bf(float f) {
    unsigned int u = __float_as_uint(f);
    unsigned int r = (u + 0x7fffu + ((u >> 16) & 1u)) >> 16;
    return (unsigned short)r;
}

// async global->LDS, 16B per lane; dest = wave-uniform base + lane*16 (HW rule)
__device__ __forceinline__ void gload16(const ushort_t* g, ushort_t* l) {
    __builtin_amdgcn_global_load_lds((__attribute__((address_space(1))) void*)(void*)g,
                                     (__attribute__((address_space(3))) void*)l, 16, 0, 0);
}

// unpack 16 bf16 (32B) -> 16 fp32
__device__ __forceinline__ void ld16bf(const ushort_t* p, float* f) {
    uint4 u0 = *(const uint4*)p;
    uint4 u1 = *(const uint4*)(p + 8);
    unsigned int w[8] = {u0.x, u0.y, u0.z, u0.w, u1.x, u1.y, u1.z, u1.w};
    #pragma unroll
    for (int i = 0; i < 8; ++i) {
        f[2 * i]     = __uint_as_float(w[i] << 16);
        f[2 * i + 1] = __uint_as_float(w[i] & 0xffff0000u);
    }
}

// ---------------- K1 prep: zero mask | h fp32->bf16 (XCD-aligned) | LDS-tiled W transpose ----------------
__global__ __launch_bounds__(256) void prep(
    const float* __restrict__ h,
    const float* __restrict__ Wq, const float* __restrict__ Wk,
    const float* __restrict__ Wv, const float* __restrict__ Wo,
    unsigned int* __restrict__ mask, ushort_t* __restrict__ hb,
    ushort_t* __restrict__ Wt, ushort_t* __restrict__ Wot) {
    __shared__ float ts[64][65];
    const int bid = blockIdx.x;
    const int t = threadIdx.x;
    if (bid < 128) {
        uint4 z = {0u, 0u, 0u, 0u};
        ((uint4*)mask)[bid * 256 + t] = z;        // 512 KB
    } else if (bid < 1152) {
        // h2bf, XCD-aligned with the QKV GEMM reader
        int j = bid - 128;                        // 0..1023
        int jj = (j & 7) * 128 + (j >> 3);
        int chunk = jj * 256 + t;                 // 262144 chunks of 8 floats
        float4 a = *(const float4*)(h + (size_t)chunk * 8);
        float4 b = *(const float4*)(h + (size_t)chunk * 8 + 4);
        ushort_t o[8] = {f2bf(a.x), f2bf(a.y), f2bf(a.z), f2bf(a.w),
                         f2bf(b.x), f2bf(b.y), f2bf(b.z), f2bf(b.w)};
        *(uint4*)(hb + (size_t)chunk * 8) = *(const uint4*)o;
    } else {
        // coalesced transpose: which W, 16 tiles of 64x64 each
        const int bid6 = bid - 1152;
        const int which = bid6 >> 4, tile = bid6 & 15;
        const int k0 = (tile >> 2) * 64, n0 = (tile & 3) * 64;
        const float* W = (which == 0) ? Wq : (which == 1) ? Wk : (which == 2) ? Wv : Wo;
        #pragma unroll
        for (int i = 0; i < 4; ++i) {
            int kr = i * 16 + (t >> 4), c4 = (t & 15) * 4;
            float4 v = *(const float4*)&W[(size_t)(k0 + kr) * 256 + n0 + c4];
            ts[kr][c4 + 0] = v.x; ts[kr][c4 + 1] = v.y;
            ts[kr][c4 + 2] = v.z; ts[kr][c4 + 3] = v.w;
        }
        __syncthreads();
        #pragma unroll
        for (int i = 0; i < 4; ++i) {
            int nr = i * 16 + (t >> 4), kc = (t & 15) * 4;
            ushort_t o[4] = {f2bf(ts[kc][nr]), f2bf(ts[kc + 1][nr]),
                             f2bf(ts[kc + 2][nr]), f2bf(ts[kc + 3][nr])};
            ushort_t* dstp = (which < 3) ? (Wt + (size_t)(which * 256 + n0 + nr) * 256 + k0 + kc)
                                         : (Wot + (size_t)(n0 + nr) * 256 + k0 + kc);
            *(uint2*)dstp = *(const uint2*)o;
        }
    }
}

// ---------------- K2: QKV GEMM (blocks 0-383, XCD-swizzled, BK=128) || mask_build (384-895) ----------------
// q/k/v outputs ROW-MAJOR [8192][256] (head-interleaved) for coalesced attn gathers.
__global__ __launch_bounds__(256) void mask_gemm(
    const int* __restrict__ src, const int* __restrict__ dst, unsigned int* __restrict__ mask,
    const ushort_t* __restrict__ A, const ushort_t* __restrict__ Bt,
    const float* __restrict__ b0, const float* __restrict__ b1, const float* __restrict__ b2,
    ushort_t* __restrict__ qb, ushort_t* __restrict__ kb, ushort_t* __restrict__ vb) {
    __shared__ ushort_t As[128 * 128];   // 32 KB
    __shared__ ushort_t Bs[128 * 128];   // 32 KB
    const int bid = blockIdx.x;
    const int t = threadIdx.x;

    if (bid >= 384) {
        // ---- mask build ----
        int tt = (bid - 384) * 256 + t;
        if (tt < EE) {
            int s = src[tt], d = dst[tt];
            int b = s / NN, r = s % NN, c = d % NN;
            atomicOr(&mask[((size_t)(b * NN + r)) * 16 + (c >> 5)], 1u << (c & 31));
        }
        if (tt < MM) {
            atomicOr(&mask[(size_t)tt * 16 + ((tt & 511) >> 5)], 1u << (tt & 31));
        }
        return;
    }

    // ---- QKV GEMM; T1 swizzle: XCD x gets contiguous 8m x 6n region (384 = 8*48, bijective) ----
    const int xcd = bid & 7, idx = bid >> 3;       // idx in [0,48)
    const int m0 = (xcd * 8 + (idx & 7)) * 128;    // 64 m-tiles
    const int n0 = (idx >> 3) * 128;               // 6 n-tiles
    const int wid = t >> 6, lane = t & 63, g = lane >> 4, c = lane & 15;
    const int wr = wid >> 1, wc = wid & 1;

    f32x4 acc[4][4];
    #pragma unroll
    for (int mi = 0; mi < 4; ++mi)
        #pragma unroll
        for (int nj = 0; nj < 4; ++nj) acc[mi][nj] = (f32x4){0.f, 0.f, 0.f, 0.f};

    // BK=128: 16 x 16B slots per row; swizzle slot ^= (row & 15), both sides (rule 21)
    #define STAGE_QKV(kt) { \
        const int k0s = (kt) * 128; \
        _Pragma("unroll") \
        for (int i = 0; i < 8; ++i) { \
            int p = i * 256 + t; \
            int row = p >> 4, ss = (p & 15) ^ (row & 15); \
            int ldoff = (i * 256 + wid * 64) * 8; \
            gload16(A  + (size_t)(m0 + row) * 256 + k0s + ss * 8, &As[ldoff]); \
            gload16(Bt + (size_t)(n0 + row) * 256 + k0s + ss * 8, &Bs[ldoff]); \
        } \
    }

    STAGE_QKV(0);
    __syncthreads();
    for (int kt = 0; kt < 2; ++kt) {
        #pragma unroll
        for (int kk = 0; kk < 4; ++kk) {
            bf16x8 av[4], bv4[4];
            #pragma unroll
            for (int mi = 0; mi < 4; ++mi) {
                int row = wr * 64 + mi * 16 + c;                 // row & 15 == c
                av[mi] = *(const bf16x8*)&As[row * 128 + (((kk * 4 + g) ^ c) << 3)];
            }
            #pragma unroll
            for (int nj = 0; nj < 4; ++nj) {
                int row = wc * 64 + nj * 16 + c;
                bv4[nj] = *(const bf16x8*)&Bs[row * 128 + (((kk * 4 + g) ^ c) << 3)];
            }
            #pragma unroll
            for (int mi = 0; mi < 4; ++mi)
                #pragma unroll
                for (int nj = 0; nj < 4; ++nj)
                    acc[mi][nj] = __builtin_amdgcn_mfma_f32_16x16x32_bf16(av[mi], bv4[nj], acc[mi][nj], 0, 0, 0);
        }
        if (kt == 0) {
            __syncthreads();
            STAGE_QKV(1);
            __syncthreads();
        }
    }

    #pragma unroll
    for (int mi = 0; mi < 4; ++mi) {
        #pragma unroll
        for (int nj = 0; nj < 4; ++nj) {
            const f32x4 av = acc[mi][nj];
            const int m_base = m0 + wr * 64 + mi * 16 + 4 * g;
            const int n_base = n0 + wc * 64 + nj * 16;
            const int z = n_base >> 8, nn = n_base & 255;
            const float* bp = (z == 0) ? b0 : (z == 1) ? b1 : b2;
            const float bias = bp[nn + c];
            ushort_t* dst2 = (z == 0) ? qb : (z == 1) ? kb : vb;
            #pragma unroll
            for (int r = 0; r < 4; ++r)
                dst2[(size_t)(m_base + r) * 256 + nn + c] = f2bf(av[r] + bias);
        }
    }
}

// ---------------- K3: sparse attention, XCD-graph-locality; row-major K/V gathers ----------------
__global__ __launch_bounds__(256) void attn_sparse3(
    const ushort_t* __restrict__ qb, const ushort_t* __restrict__ kb,
    const ushort_t* __restrict__ vb, const unsigned int* __restrict__ mask,
    ushort_t* __restrict__ attnb) {
    __shared__ ushort_t colsS[4][64];
    const int wid = threadIdx.x >> 6, lane = threadIdx.x & 63;
    const int xcd = blockIdx.x & 7, j = blockIdx.x >> 3;        // 2048 blocks
    const int b = xcd * 2 + (j >> 7);                           // graph
    const int q = (j & 127) * 4 + wid;
    const int row = b * 512 + q;
    const int e2 = lane >> 4, h = (lane >> 1) & 7, half = lane & 1;
    const float SCALE = 0.17677669529663687f;  // 1/sqrt(32)

    unsigned int word = (lane < 16) ? mask[(size_t)row * 16 + lane] : 0u;
    int pc = __popc(word);
    int pre = pc;
    #pragma unroll
    for (int o = 1; o < 16; o <<= 1) {
        int v = __shfl_up(pre, o);
        if ((lane & 15) >= o) pre += v;
    }
    int off = pre - pc;
    while (word) {
        int bit = __ffs(word) - 1;
        word &= word - 1;
        if (off < 64) colsS[wid][off] = (ushort_t)(lane * 32 + bit);
        ++off;
    }
    int cnt = __shfl(pre, 15);
    cnt = cnt < 64 ? cnt : 64;

    const size_t rowbase = (size_t)b * 512;
    const int hd0 = h * 32 + half * 16;           // column offset within the 256-wide row
    float qf[16];
    ld16bf(qb + (rowbase + q) * 256 + hd0, qf);

    float acc[16];
    #pragma unroll
    for (int d = 0; d < 16; ++d) acc[d] = 0.f;
    float l = 0.f;

    #pragma unroll 2
    for (int e = 0; e < cnt; e += 4) {
        int slot = e + e2;
        int col = colsS[wid][slot < cnt ? slot : 0];
        const ushort_t* kp = kb + (rowbase + col) * 256 + hd0;
        const ushort_t* vp = vb + (rowbase + col) * 256 + hd0;
        float kf[16], vf[16];
        ld16bf(kp, kf);
        ld16bf(vp, vf);
        float s0 = 0.f, s1 = 0.f;
        #pragma unroll
        for (int d = 0; d < 8; ++d) {
            s0 = fmaf(qf[d], kf[d], s0);
            s1 = fmaf(qf[8 + d], kf[8 + d], s1);
        }
        float s = s0 + s1;
        s += __shfl_xor(s, 1);
        float p = (slot < cnt) ? __expf(fmaf(s, SCALE, -16.0f)) : 0.f;
        l += p;
        #pragma unroll
        for (int d = 0; d < 16; ++d) acc[d] = fmaf(p, vf[d], acc[d]);
    }

    #pragma unroll
    for (int d = 0; d < 16; ++d) {
        acc[d] += __shfl_xor(acc[d], 16);
        acc[d] += __shfl_xor(acc[d], 32);
    }
    l += __shfl_xor(l, 16);
    l += __shfl_xor(l, 32);

    if (e2 == 0) {
        float rl = 1.0f / l;
        ushort_t o[16];
        #pragma unroll
        for (int d = 0; d < 16; ++d) o[d] = f2bf(acc[d] * rl);
        ushort_t* op = attnb + (size_t)row * 256 + hd0;
        *(uint4*)op       = *(const uint4*)o;
        *(uint4*)(op + 8) = *(const uint4*)(o + 8);
    }
}

// ---------------- K4: 64x64 MFMA GEMM out-proj, BK=128, XCD-aligned with attn writer ----------------
__global__ __launch_bounds__(256) void gemm_out(
    const ushort_t* __restrict__ A, const ushort_t* __restrict__ Bt,
    const float* __restrict__ b0, float* __restrict__ fout) {
    __shared__ ushort_t As[64 * 128];    // 16 KB
    __shared__ ushort_t Bs[64 * 128];    // 16 KB
    const int t = threadIdx.x;
    const int lin = blockIdx.x;
    const int xcd = lin & 7, idx = lin >> 3;        // idx in [0,64)
    const int m0 = (xcd * 16 + (idx & 15)) * 64;
    const int n0 = (idx >> 4) * 64;
    const int wid = t >> 6, lane = t & 63, g = lane >> 4, c = lane & 15;
    const int wr = wid >> 1, wc = wid & 1;

    f32x4 acc00 = {0.f,0.f,0.f,0.f}, acc01 = acc00, acc10 = acc00, acc11 = acc00;

    #define STAGE_OUT(kt) { \
        const int k0s = (kt) * 128; \
        _Pragma("unroll") \
        for (int i = 0; i < 4; ++i) { \
            int p = i * 256 + t; \
            int row = p >> 4, ss = (p & 15) ^ (row & 15); \
            int ldoff = (i * 256 + wid * 64) * 8; \
            gload16(A  + (size_t)(m0 + row) * 256 + k0s + ss * 8, &As[ldoff]); \
            gload16(Bt + (size_t)(n0 + row) * 256 + k0s + ss * 8, &Bs[ldoff]); \
        } \
    }

    STAGE_OUT(0);
    __syncthreads();
    for (int kt = 0; kt < 2; ++kt) {
        #pragma unroll
        for (int kk = 0; kk < 4; ++kk) {
            int rowa0 = wr * 32 + c, rowa1 = wr * 32 + 16 + c;
            int rowb0 = wc * 32 + c, rowb1 = wc * 32 + 16 + c;
            int sw = ((kk * 4 + g) ^ c) << 3;
            bf16x8 a0 = *(const bf16x8*)&As[rowa0 * 128 + sw];
            bf16x8 a1 = *(const bf16x8*)&As[rowa1 * 128 + sw];
            bf16x8 bb0 = *(const bf16x8*)&Bs[rowb0 * 128 + sw];
            bf16x8 bb1 = *(const bf16x8*)&Bs[rowb1 * 128 + sw];
            acc00 = __builtin_amdgcn_mfma_f32_16x16x32_bf16(a0, bb0, acc00, 0, 0, 0);
            acc01 = __builtin_amdgcn_mfma_f32_16x16x32_bf16(a0, bb1, acc01, 0, 0, 0);
            acc10 = __builtin_amdgcn_mfma_f32_16x16x32_bf16(a1, bb0, acc10, 0, 0, 0);
            acc11 = __builtin_amdgcn_mfma_f32_16x16x32_bf16(a1, bb1, acc11, 0, 0, 0);
        }
        if (kt == 0) {
            __syncthreads();
            STAGE_OUT(1);
            __syncthreads();
        }
    }

    #pragma unroll
    for (int mi = 0; mi < 2; ++mi) {
        #pragma unroll
        for (int nj = 0; nj < 2; ++nj) {
            const f32x4 av = (mi == 0) ? (nj == 0 ? acc00 : acc01) : (nj == 0 ? acc10 : acc11);
            const int m_base = m0 + wr * 32 + mi * 16 + 4 * g;
            const int n_base = n0 + wc * 32 + nj * 16;
            const float bias = b0[n_base + c];
            #pragma unroll
            for (int r = 0; r < 4; ++r)
                fout[(size_t)(m_base + r) * 256 + n_base + c] = av[r] + bias;
        }
    }
}

extern "C" void kernel_launch(void* const* d_in, const int* in_sizes, int n_in,
                              void* d_out, int out_size, void* d_ws, size_t ws_size,
                              hipStream_t stream) {
    const float* hin = (const float*)d_in[0];
    const int* src   = (const int*)d_in[1];
    const int* dst   = (const int*)d_in[2];
    const float* Wq  = (const float*)d_in[3];
    const float* bq  = (const float*)d_in[4];
    const float* Wk  = (const float*)d_in[5];
    const float* bk  = (const float*)d_in[6];
    const float* Wv  = (const float*)d_in[7];
    const float* bv  = (const float*)d_in[8];
    const float* Wo  = (const float*)d_in[9];
    const float* bo  = (const float*)d_in[10];

    char* ws = (char*)d_ws;
    unsigned int* mask = (unsigned int*)ws;                      // 512 KB
    ushort_t* hb    = (ushort_t*)(ws + 2129920);                 // 4 MB
    ushort_t* qb    = (ushort_t*)(ws + 6324224);                 // 4 MB
    ushort_t* kb    = (ushort_t*)(ws + 10518528);                // 4 MB
    ushort_t* vb    = (ushort_t*)(ws + 14712832);                // 4 MB
    ushort_t* attnb = (ushort_t*)(ws + 18907136);                // 4 MB
    ushort_t* Wt    = (ushort_t*)(ws + 23101440);                // 384 KB
    ushort_t* Wot   = (ushort_t*)(ws + 23494656);                // 128 KB
    float* out = (float*)d_out;

    prep<<<1216, 256, 0, stream>>>(hin, Wq, Wk, Wv, Wo, mask, hb, Wt, Wot);
    mask_gemm<<<896, 256, 0, stream>>>(src, dst, mask, hb, Wt, bq, bk, bv, qb, kb, vb);
    attn_sparse3<<<2048, 256, 0, stream>>>(qb, kb, vb, mask, attnb);
    gemm_out<<<512, 256, 0, stream>>>(attnb, Wot, bo, out);
}